// Round 12
// baseline (5156.742 us; speedup 1.0000x reference)
//
#include <hip/hip_runtime.h>
#include <stdint.h>

// GRU: L=2, D=H=1024, S=512, B=32.
// Phase 1: xg GEMM (bf16 MFMA) — unchanged from R8.
// Phase 2: persistent recurrence, 256 single-wave WGs. R12: K-SPLIT pairs.
//   WG = (l, gs32, bhalf, khalf): owns 32 g-rows x 16 b-cols, but stages and
//   multiplies only its K-half (512) — halves the dominant LLC-read bytes.
//   Partner pair (khalf^1) exchanges bf16 partial pre-activations (small),
//   both redundantly compute gates for all 32 rows; each publishes its own
//   16-row tile of h/rh (flag structure identical to R8: 64 producers/group).
//   All sync = proven R8 release-flag protocol (st_wt + vmcnt(0) + flag).

typedef __attribute__((ext_vector_type(8))) short bf16x8;
typedef __attribute__((ext_vector_type(4))) float f32x4;
typedef __attribute__((ext_vector_type(4))) unsigned int u32x4;

#define NL 2
#define SB 32
#define HD 1024
#define SEQ 512

// ---- workspace layout (bytes) ----
#define XG_ELEMS   ((size_t)SEQ*6*SB*HD)
#define XG_OFF     0ull
#define XBF_OFF    (XG_OFF + XG_ELEMS*2)
#define XBF_ELEMS  ((size_t)SEQ*SB*HD)
#define WBF_OFF    (XBF_OFF + XBF_ELEMS*2)
#define WBF_ELEMS  ((size_t)6*HD*HD)
#define HBUF_OFF   (WBF_OFF + WBF_ELEMS*2)      // bf16 h   [64 brow][256 u64]
#define HBUF_BYTES ((size_t)NL*SB*256*8)
#define RBUF_OFF   (HBUF_OFF + HBUF_BYTES)      // bf16 r*h
#define HFLG_OFF   (RBUF_OFF + HBUF_BYTES)      // 4 grp x 64 pid x 16 u32
#define FLG_WORDS  (4*64*16)
#define RFLG_OFF   (HFLG_OFF + FLG_WORDS*4)
#define PAF_OFF    (RFLG_OFF + FLG_WORDS*4)     // 256 pidx x 16 u32
#define PBF_OFF    (PAF_OFF + 256*16*4)
#define CLR_BYTES  ((PBF_OFF + 256*16*4) - HFLG_OFF)
#define PA_OFF     (PBF_OFF + 256*16*4)         // 256 pidx x 256 u64 (z,r partials)
#define PB_OFF     (PA_OFF + (size_t)256*256*8) // 256 pidx x 128 u64 (hh partials)
#define WS_NEED    (PB_OFF + (size_t)256*128*8)

__device__ __forceinline__ unsigned short f2bf(float f) {
  unsigned int u = __float_as_uint(f);
  u = u + 0x7fffu + ((u >> 16) & 1u);
  return (unsigned short)(u >> 16);
}
__device__ __forceinline__ float bf2f(unsigned int bits) {
  return __uint_as_float(bits << 16);
}
__device__ __forceinline__ f32x4 unpack4(uint2 u) {
  f32x4 v;
  v[0] = bf2f(u.x & 0xffffu); v[1] = bf2f(u.x >> 16);
  v[2] = bf2f(u.y & 0xffffu); v[3] = bf2f(u.y >> 16);
  return v;
}
__device__ __forceinline__ f32x4 unpack4q(unsigned long long q) {
  uint2 u = { (unsigned)q, (unsigned)(q >> 32) };
  return unpack4(u);
}

__device__ __forceinline__ void st_wt(unsigned long long* p, unsigned long long v) {
  __hip_atomic_store(p, v, __ATOMIC_RELAXED, __HIP_MEMORY_SCOPE_AGENT);
}
__device__ __forceinline__ unsigned long long ld_wt(const unsigned long long* p) {
  return __hip_atomic_load(p, __ATOMIC_RELAXED, __HIP_MEMORY_SCOPE_AGENT);
}
__device__ __forceinline__ unsigned ld_flag(const unsigned* p) {
  return __hip_atomic_load(p, __ATOMIC_RELAXED, __HIP_MEMORY_SCOPE_AGENT);
}
__device__ __forceinline__ void st_flag(unsigned* p, unsigned v) {
  __hip_atomic_store(p, v, __ATOMIC_RELAXED, __HIP_MEMORY_SCOPE_AGENT);
}
__device__ __forceinline__ unsigned long long pack4(const f32x4 v) {
  ushort4 o = { f2bf(v[0]), f2bf(v[1]), f2bf(v[2]), f2bf(v[3]) };
  unsigned long long q; __builtin_memcpy(&q, &o, 8);
  return q;
}

// ---------------- fp32 -> bf16 convert ----------------
__global__ void cvt_f32_bf16(const float* __restrict__ src,
                             unsigned short* __restrict__ dst, int n4) {
  int i = blockIdx.x * blockDim.x + threadIdx.x;
  int st = gridDim.x * blockDim.x;
  for (; i < n4; i += st) {
    float4 v = ((const float4*)src)[i];
    ushort4 o = { f2bf(v.x), f2bf(v.y), f2bf(v.z), f2bf(v.w) };
    ((ushort4*)dst)[i] = o;
  }
}

// ---------------- phase 1 GEMM (unchanged R8) ----------------
__global__ __launch_bounds__(256) void gemm_xg(const unsigned short* __restrict__ Wb,
                                               const unsigned short* __restrict__ xb,
                                               unsigned short* __restrict__ xg) {
  __shared__ short As[128 * 32];
  __shared__ short Bs[128 * 32];
  const int lg = blockIdx.z;
  const int m0 = blockIdx.y * 128;
  const int n0 = blockIdx.x * 128;
  const int tid = threadIdx.x, w = tid >> 6, lane = tid & 63;
  const int wm = (w >> 1) * 64, wn = (w & 1) * 64;
  const unsigned short* Ag = Wb + (size_t)lg * HD * HD;

  f32x4 acc[4][4] = {};

  for (int k0 = 0; k0 < HD; k0 += 32) {
    __syncthreads();
#pragma unroll
    for (int i = 0; i < 2; i++) {
      int off = (i * 256 + tid) * 16;
      int rr = off >> 6;
      int cc = (off >> 4) & 3;
      *(uint4*)((char*)As + off) = *(const uint4*)(Ag + (size_t)(m0 + rr) * HD + k0 + cc * 8);
      *(uint4*)((char*)Bs + off) = *(const uint4*)(xb + (size_t)(n0 + rr) * HD + k0 + cc * 8);
    }
    __syncthreads();
    bf16x8 af[4], bf[4];
#pragma unroll
    for (int mi = 0; mi < 4; mi++)
      af[mi] = *(const bf16x8*)&As[(wm + mi * 16 + (lane & 15)) * 32 + ((lane >> 4) << 3)];
#pragma unroll
    for (int ni = 0; ni < 4; ni++)
      bf[ni] = *(const bf16x8*)&Bs[(wn + ni * 16 + (lane & 15)) * 32 + ((lane >> 4) << 3)];
#pragma unroll
    for (int mi = 0; mi < 4; mi++)
#pragma unroll
      for (int ni = 0; ni < 4; ni++)
        acc[mi][ni] = __builtin_amdgcn_mfma_f32_16x16x32_bf16(af[mi], bf[ni], acc[mi][ni], 0, 0, 0);
  }

#pragma unroll
  for (int mi = 0; mi < 4; mi++) {
    int g = m0 + wm + mi * 16 + ((lane >> 4) << 2);
#pragma unroll
    for (int ni = 0; ni < 4; ni++) {
      int n = n0 + wn + ni * 16 + (lane & 15);
      int s = n >> 5, b = n & 31;
      ushort4 o = { f2bf(acc[mi][ni][0]), f2bf(acc[mi][ni][1]),
                    f2bf(acc[mi][ni][2]), f2bf(acc[mi][ni][3]) };
      *(ushort4*)(xg + ((size_t)(s * 6 + lg)) * (SB * HD) + (size_t)b * HD + g) = o;
    }
  }
}

// ---------------- phase 2: recurrence ----------------
// A-frag: row rt*16+(lane&15) of this WG's 32 rows; k-local kk*32+(lane>>4)*8
__device__ __forceinline__ bf16x8 afrag2(const short* wlds, int gate, int rt,
                                         int lane, int kk) {
  int r = rt * 16 + (lane & 15);
  int sck = (kk * 4 + (lane >> 4)) ^ (r & 7);
  return *(const bf16x8*)&wlds[gate * 16384 + r * 512 + sck * 8];
}

__device__ __forceinline__ void flag_wait64(const unsigned* fgrp, int lane, unsigned tag) {
  bool ok;
  do { ok = (ld_flag(&fgrp[lane * 16]) >= tag); } while (!__all(ok));
}
__device__ __forceinline__ void flag_wait1(const unsigned* f, unsigned tag) {
  while (ld_flag(f) < tag) {}
}

// stage this lane's 256B of the K-half: 16 wide LLC-coherent plain loads
__device__ __forceinline__ void stage16(const unsigned long long* p, u32x4* vv) {
#pragma unroll
  for (int kk = 0; kk < 16; kk++) {
    asm volatile("global_load_dwordx4 %0, %1, off sc0 sc1"
                 : "=v"(vv[kk]) : "v"(p + kk * 8) : "memory");
  }
  asm volatile("s_waitcnt vmcnt(0)" ::: "memory");
  __builtin_amdgcn_sched_barrier(0);
}

__global__ __launch_bounds__(64, 1) void gru_rec(
    const float* __restrict__ h0,
    const float* __restrict__ Uz, const float* __restrict__ Ur, const float* __restrict__ Uh,
    const float* __restrict__ bz, const float* __restrict__ br, const float* __restrict__ bh,
    const unsigned short* __restrict__ xg,
    unsigned long long* __restrict__ hbuf,
    unsigned long long* __restrict__ rbuf,
    unsigned* __restrict__ hflg,
    unsigned* __restrict__ rflg,
    unsigned long long* __restrict__ pa,
    unsigned long long* __restrict__ pb,
    unsigned* __restrict__ paf,
    unsigned* __restrict__ pbf,
    float* __restrict__ out) {
  __shared__ short wlds[3 * 16384];     // 96 KB: 3 gates x 32 rows x 512 k-half

  const int wg = blockIdx.x;            // 256 WGs, one wave each
  const int l = wg >> 7;
  const int r7 = wg & 127;
  const int kh = r7 >> 6;               // K-half owner (0/1)
  const int bhalf = (r7 >> 5) & 1;
  const int gs = r7 & 31;               // 32-row g-slice
  const int g0 = gs * 32;
  const int lane = threadIdx.x;
  const int col = lane & 15;
  const int sub = lane >> 4;
  const int rb = sub << 2;
  const int grp = l * 2 + bhalf;        // h/rh exchange group 0..3
  const int pid = gs * 2 + kh;          // this WG's 16-row publisher id
  const int pidx = ((l * 32 + gs) * 2 + bhalf) * 2 + kh;  // pair entry

  // ---- load U slices into LDS: rows g0..g0+32, k in [kh*512, kh*512+512) ----
  const float* Us[3] = { Uz, Ur, Uh };
#pragma unroll
  for (int gate = 0; gate < 3; gate++) {
    const float* U = Us[gate] + (size_t)l * HD * HD + (size_t)g0 * HD + kh * 512;
    for (int it = 0; it < 32; it++) {
      int chunk = it * 64 + lane;       // 2048 chunks of 8 elems
      int r = chunk >> 6;               // 64 chunks per row
      int ck = chunk & 63;
      const float* src = U + (size_t)r * HD + ck * 8;
      float4 a = *(const float4*)src;
      float4 bq = *(const float4*)(src + 4);
      bf16x8 o;
      o[0] = (short)f2bf(a.x); o[1] = (short)f2bf(a.y);
      o[2] = (short)f2bf(a.z); o[3] = (short)f2bf(a.w);
      o[4] = (short)f2bf(bq.x); o[5] = (short)f2bf(bq.y);
      o[6] = (short)f2bf(bq.z); o[7] = (short)f2bf(bq.w);
      int sck = ck ^ (r & 7);
      *(bf16x8*)&wlds[gate * 16384 + r * 512 + sck * 8] = o;
    }
  }
  asm volatile("s_waitcnt lgkmcnt(0)" ::: "memory");  // single wave: LDS ready

  f32x4 vbz[2], vbr[2], vbh[2];
#pragma unroll
  for (int rt = 0; rt < 2; rt++) {
    vbz[rt] = *(const f32x4*)(bz + l * HD + g0 + rt * 16 + rb);
    vbr[rt] = *(const f32x4*)(br + l * HD + g0 + rt * 16 + rb);
    vbh[rt] = *(const f32x4*)(bh + l * HD + g0 + rt * 16 + rb);
  }

  const int brow = l * SB + bhalf * 16 + col;
  f32x4 hreg[2];
#pragma unroll
  for (int rt = 0; rt < 2; rt++)
    hreg[rt] = *(const f32x4*)(h0 + (size_t)brow * HD + g0 + rt * 16 + rb);

  // h/rh exchange: publish own kh-tile rows, stage own K-half
  unsigned long long* hdst = hbuf + ((size_t)brow << 8) + ((g0 + kh * 16 + rb) >> 2);
  unsigned long long* rdst = rbuf + ((size_t)brow << 8) + ((g0 + kh * 16 + rb) >> 2);
  const unsigned long long* hp = hbuf + ((size_t)brow << 8) + kh * 128 + sub * 2;
  const unsigned long long* rp = rbuf + ((size_t)brow << 8) + kh * 128 + sub * 2;
  const unsigned* hf_g = hflg + grp * 64 * 16;
  const unsigned* rf_g = rflg + grp * 64 * 16;
  unsigned* myhf = hflg + (grp * 64 + pid) * 16;
  unsigned* myrf = rflg + (grp * 64 + pid) * 16;

  // partial exchange (pair = pidx^1)
  unsigned long long* paw = pa + (size_t)pidx * 256;
  const unsigned long long* par = pa + (size_t)(pidx ^ 1) * 256;
  unsigned long long* pbw = pb + (size_t)pidx * 128;
  const unsigned long long* pbr = pb + (size_t)(pidx ^ 1) * 128;
  unsigned* pafw = paf + pidx * 16;
  const unsigned* pafr = paf + (pidx ^ 1) * 16;
  unsigned* pbfw = pbf + pidx * 16;
  const unsigned* pbfr = pbf + (pidx ^ 1) * 16;

  // publish initial h tile
  st_wt(hdst, pack4(hreg[kh]));
  asm volatile("s_waitcnt vmcnt(0)" ::: "memory");
  if (lane == 0) st_flag(myhf, 1u);

  // xg loads: current step (both row-tiles), prefetched one step ahead
  uint2 xc[3][2], xn[3][2];
  {
    size_t xb0 = ((size_t)l * 3) * (SB * HD) + (size_t)(bhalf * 16 + col) * HD + g0 + rb;
#pragma unroll
    for (int g3 = 0; g3 < 3; g3++)
#pragma unroll
      for (int rt = 0; rt < 2; rt++)
        xc[g3][rt] = *(const uint2*)(xg + xb0 + g3 * (SB * HD) + rt * 16);
  }

  u32x4 vv[16];

  for (int s = 0; s < SEQ; s++) {
    const unsigned tag = (unsigned)(s + 1);

    // ---- phase A: z, r ----
    flag_wait64(hf_g, lane, tag);
    stage16(hp, vv);
    f32x4 az[2] = { {0,0,0,0}, {0,0,0,0} }, ar[2] = { {0,0,0,0}, {0,0,0,0} };
#pragma unroll
    for (int kk = 0; kk < 16; kk++) {
      union { u32x4 w; bf16x8 b; } u;
      u.w = vv[kk];
#pragma unroll
      for (int rt = 0; rt < 2; rt++) {
        az[rt] = __builtin_amdgcn_mfma_f32_16x16x32_bf16(afrag2(wlds, 0, rt, lane, kk), u.b, az[rt], 0, 0, 0);
        ar[rt] = __builtin_amdgcn_mfma_f32_16x16x32_bf16(afrag2(wlds, 1, rt, lane, kk), u.b, ar[rt], 0, 0, 0);
      }
    }
    // publish bf16 partials (z,r) and fetch partner's
#pragma unroll
    for (int rt = 0; rt < 2; rt++) {
      st_wt(paw + (0 * 16 + col) * 8 + rt * 4 + sub, pack4(az[rt]));
      st_wt(paw + (1 * 16 + col) * 8 + rt * 4 + sub, pack4(ar[rt]));
    }
    asm volatile("s_waitcnt vmcnt(0)" ::: "memory");
    if (lane == 0) st_flag(pafw, tag);
    flag_wait1(pafr, tag);
    f32x4 pz[2], pr[2];
#pragma unroll
    for (int rt = 0; rt < 2; rt++) {
      pz[rt] = unpack4q(ld_wt(par + (0 * 16 + col) * 8 + rt * 4 + sub));
      pr[rt] = unpack4q(ld_wt(par + (1 * 16 + col) * 8 + rt * 4 + sub));
    }
    f32x4 z[2], rh[2];
#pragma unroll
    for (int rt = 0; rt < 2; rt++) {
      f32x4 xzf = unpack4(xc[0][rt]), xrf = unpack4(xc[1][rt]);
#pragma unroll
      for (int j = 0; j < 4; j++) {
        float za = xzf[j] + vbz[rt][j] + az[rt][j] + pz[rt][j];
        float ra = xrf[j] + vbr[rt][j] + ar[rt][j] + pr[rt][j];
        z[rt][j] = 1.f / (1.f + __expf(-za));
        rh[rt][j] = (1.f / (1.f + __expf(-ra))) * hreg[rt][j];
      }
    }
    st_wt(rdst, pack4(rh[kh]));
    asm volatile("s_waitcnt vmcnt(0)" ::: "memory");
    if (lane == 0) st_flag(myrf, tag);

    // prefetch next step's xg (overlaps phase-B exchange latency)
    {
      int sn = (s + 1 < SEQ) ? s + 1 : s;
      size_t xbn = ((size_t)sn * 6 + l * 3) * (SB * HD) + (size_t)(bhalf * 16 + col) * HD + g0 + rb;
#pragma unroll
      for (int g3 = 0; g3 < 3; g3++)
#pragma unroll
        for (int rt = 0; rt < 2; rt++)
          xn[g3][rt] = *(const uint2*)(xg + xbn + g3 * (SB * HD) + rt * 16);
    }

    // ---- phase B: hh, h update ----
    flag_wait64(rf_g, lane, tag);
    stage16(rp, vv);
    f32x4 ah[2] = { {0,0,0,0}, {0,0,0,0} };
#pragma unroll
    for (int kk = 0; kk < 16; kk++) {
      union { u32x4 w; bf16x8 b; } u;
      u.w = vv[kk];
#pragma unroll
      for (int rt = 0; rt < 2; rt++)
        ah[rt] = __builtin_amdgcn_mfma_f32_16x16x32_bf16(afrag2(wlds, 2, rt, lane, kk), u.b, ah[rt], 0, 0, 0);
    }
#pragma unroll
    for (int rt = 0; rt < 2; rt++)
      st_wt(pbw + col * 8 + rt * 4 + sub, pack4(ah[rt]));
    asm volatile("s_waitcnt vmcnt(0)" ::: "memory");
    if (lane == 0) st_flag(pbfw, tag);
    flag_wait1(pbfr, tag);
    f32x4 ph[2];
#pragma unroll
    for (int rt = 0; rt < 2; rt++)
      ph[rt] = unpack4q(ld_wt(pbr + col * 8 + rt * 4 + sub));

#pragma unroll
    for (int rt = 0; rt < 2; rt++) {
      f32x4 xhf = unpack4(xc[2][rt]);
#pragma unroll
      for (int j = 0; j < 4; j++) {
        float ha = xhf[j] + vbh[rt][j] + ah[rt][j] + ph[rt][j];
        float e = __expf(2.f * ha);                    // tanh via exp
        float hh = 1.f - 2.f / (e + 1.f);
        hreg[rt][j] = (1.f - z[rt][j]) * hreg[rt][j] + z[rt][j] * hh;
      }
    }
    st_wt(hdst, pack4(hreg[kh]));
    asm volatile("s_waitcnt vmcnt(0)" ::: "memory");
    if (lane == 0) st_flag(myhf, tag + 1);

    if (l == 1)      // output stream is LAST layer only; each WG writes its kh tile
      *(f32x4*)(out + (size_t)s * (SB * HD) + (size_t)(bhalf * 16 + col) * HD + g0 + kh * 16 + rb) = hreg[kh];
    if (s == SEQ - 1)
      *(f32x4*)(out + (size_t)SEQ * SB * HD + (size_t)brow * HD + g0 + kh * 16 + rb) = hreg[kh];

#pragma unroll
    for (int g3 = 0; g3 < 3; g3++)
#pragma unroll
      for (int rt = 0; rt < 2; rt++)
        xc[g3][rt] = xn[g3][rt];
  }
}

extern "C" void kernel_launch(void* const* d_in, const int* in_sizes, int n_in,
                              void* d_out, int out_size, void* d_ws, size_t ws_size,
                              hipStream_t stream) {
  const float* x  = (const float*)d_in[0];
  const float* h0 = (const float*)d_in[1];
  const float* Wz = (const float*)d_in[2];
  const float* Wr = (const float*)d_in[3];
  const float* Wh = (const float*)d_in[4];
  const float* Uz = (const float*)d_in[5];
  const float* Ur = (const float*)d_in[6];
  const float* Uh = (const float*)d_in[7];
  const float* bz = (const float*)d_in[8];
  const float* br = (const float*)d_in[9];
  const float* bh = (const float*)d_in[10];

  char* ws = (char*)d_ws;
  unsigned short* xg  = (unsigned short*)(ws + XG_OFF);
  unsigned short* xbf = (unsigned short*)(ws + XBF_OFF);
  unsigned short* wbf = (unsigned short*)(ws + WBF_OFF);

  // clear all flags (hflg, rflg, paf, pbf are contiguous); replay-safe
  hipMemsetAsync(ws + HFLG_OFF, 0, CLR_BYTES, stream);

  cvt_f32_bf16<<<1024, 256, 0, stream>>>(x, xbf, (int)(XBF_ELEMS / 4));
  const float* Wsrc[3] = { Wz, Wr, Wh };
  for (int gate = 0; gate < 3; gate++)
    for (int l = 0; l < 2; l++)
      cvt_f32_bf16<<<512, 256, 0, stream>>>(Wsrc[gate] + (size_t)l * HD * HD,
                                            wbf + ((size_t)(l * 3 + gate)) * HD * HD,
                                            HD * HD / 4);

  gemm_xg<<<dim3(128, 8, 6), 256, 0, stream>>>(wbf, xbf, xg);

  gru_rec<<<256, 64, 0, stream>>>(h0, Uz, Ur, Uh, bz, br, bh, xg,
                                  (unsigned long long*)(ws + HBUF_OFF),
                                  (unsigned long long*)(ws + RBUF_OFF),
                                  (unsigned*)(ws + HFLG_OFF),
                                  (unsigned*)(ws + RFLG_OFF),
                                  (unsigned long long*)(ws + PA_OFF),
                                  (unsigned long long*)(ws + PB_OFF),
                                  (unsigned*)(ws + PAF_OFF),
                                  (unsigned*)(ws + PBF_OFF),
                                  (float*)d_out);
}

// Round 13
// 3820.880 us; speedup vs baseline: 1.3496x; 1.3496x over previous
//
#include <hip/hip_runtime.h>
#include <stdint.h>

// GRU: L=2, D=H=1024, S=512, B=32.
// Phase 1: xg[s,l,gate,b,h] = x[s,b,:] @ W[l,gate,h,:]^T  (bf16 MFMA GEMM)
// Phase 2: persistent recurrence, 256 single-wave WGs (16x16 (g,b) tile,
//   full K=1024 per wave). U-slices LDS-resident (96 KB). Cross-WG exchange
//   = R8 release-flag protocol (best measured): untagged bf16 data stores
//   (agent-scope 8B atomics), s_waitcnt vmcnt(0) release, per-producer flag;
//   consumer polls 64 flags (1/lane) then wide plain LLC loads (sc0 sc1).
// R13 critical-path shaving (no protocol change):
//   (a) r-first: phase A computes ONLY Ur*h, publishes r*h immediately;
//       Uz*h + z sigmoid run after the publish, hidden under phase-B detect.
//   (b) split-wait staging: vmcnt(16) -> MFMA chunks 0-15 overlap the
//       return of chunks 16-31 (vmcnt retires in order; sched_barrier(0)
//       after each wait keeps MFMAs from hoisting past it).

typedef __attribute__((ext_vector_type(8))) short bf16x8;
typedef __attribute__((ext_vector_type(4))) float f32x4;
typedef __attribute__((ext_vector_type(4))) unsigned int u32x4;

#define NL 2
#define SB 32
#define HD 1024
#define SEQ 512

// ---- workspace layout (bytes) ----
#define XG_ELEMS   ((size_t)SEQ*6*SB*HD)
#define XG_OFF     0ull
#define XBF_OFF    (XG_OFF + XG_ELEMS*2)
#define XBF_ELEMS  ((size_t)SEQ*SB*HD)
#define WBF_OFF    (XBF_OFF + XBF_ELEMS*2)
#define WBF_ELEMS  ((size_t)6*HD*HD)
#define HBUF_OFF   (WBF_OFF + WBF_ELEMS*2)      // bf16 h   [L][B][H]
#define HBUF_BYTES ((size_t)NL*SB*HD*2)
#define RBUF_OFF   (HBUF_OFF + HBUF_BYTES)      // bf16 r*h [L][B][H]
#define HFLG_OFF   (RBUF_OFF + HBUF_BYTES)      // 4 grp x 64 prod x 16 u32
#define FLG_WORDS  (4*64*16)
#define RFLG_OFF   (HFLG_OFF + FLG_WORDS*4)
#define WS_NEED    (RFLG_OFF + FLG_WORDS*4)

__device__ __forceinline__ unsigned short f2bf(float f) {
  unsigned int u = __float_as_uint(f);
  u = u + 0x7fffu + ((u >> 16) & 1u);
  return (unsigned short)(u >> 16);
}
__device__ __forceinline__ float bf2f(unsigned int bits) {
  return __uint_as_float(bits << 16);
}
__device__ __forceinline__ f32x4 unpack4(uint2 u) {
  f32x4 v;
  v[0] = bf2f(u.x & 0xffffu); v[1] = bf2f(u.x >> 16);
  v[2] = bf2f(u.y & 0xffffu); v[3] = bf2f(u.y >> 16);
  return v;
}

__device__ __forceinline__ void st_wt(unsigned long long* p, unsigned long long v) {
  __hip_atomic_store(p, v, __ATOMIC_RELAXED, __HIP_MEMORY_SCOPE_AGENT);
}
__device__ __forceinline__ unsigned ld_flag(const unsigned* p) {
  return __hip_atomic_load(p, __ATOMIC_RELAXED, __HIP_MEMORY_SCOPE_AGENT);
}
__device__ __forceinline__ void st_flag(unsigned* p, unsigned v) {
  __hip_atomic_store(p, v, __ATOMIC_RELAXED, __HIP_MEMORY_SCOPE_AGENT);
}

// ---------------- fp32 -> bf16 convert ----------------
__global__ void cvt_f32_bf16(const float* __restrict__ src,
                             unsigned short* __restrict__ dst, int n4) {
  int i = blockIdx.x * blockDim.x + threadIdx.x;
  int st = gridDim.x * blockDim.x;
  for (; i < n4; i += st) {
    float4 v = ((const float4*)src)[i];
    ushort4 o = { f2bf(v.x), f2bf(v.y), f2bf(v.z), f2bf(v.w) };
    ((ushort4*)dst)[i] = o;
  }
}

// ---------------- phase 1 GEMM ----------------
__global__ __launch_bounds__(256) void gemm_xg(const unsigned short* __restrict__ Wb,
                                               const unsigned short* __restrict__ xb,
                                               unsigned short* __restrict__ xg) {
  __shared__ short As[128 * 32];
  __shared__ short Bs[128 * 32];
  const int lg = blockIdx.z;
  const int m0 = blockIdx.y * 128;
  const int n0 = blockIdx.x * 128;
  const int tid = threadIdx.x, w = tid >> 6, lane = tid & 63;
  const int wm = (w >> 1) * 64, wn = (w & 1) * 64;
  const unsigned short* Ag = Wb + (size_t)lg * HD * HD;

  f32x4 acc[4][4] = {};

  for (int k0 = 0; k0 < HD; k0 += 32) {
    __syncthreads();
#pragma unroll
    for (int i = 0; i < 2; i++) {
      int off = (i * 256 + tid) * 16;
      int rr = off >> 6;
      int cc = (off >> 4) & 3;
      *(uint4*)((char*)As + off) = *(const uint4*)(Ag + (size_t)(m0 + rr) * HD + k0 + cc * 8);
      *(uint4*)((char*)Bs + off) = *(const uint4*)(xb + (size_t)(n0 + rr) * HD + k0 + cc * 8);
    }
    __syncthreads();
    bf16x8 af[4], bf[4];
#pragma unroll
    for (int mi = 0; mi < 4; mi++)
      af[mi] = *(const bf16x8*)&As[(wm + mi * 16 + (lane & 15)) * 32 + ((lane >> 4) << 3)];
#pragma unroll
    for (int ni = 0; ni < 4; ni++)
      bf[ni] = *(const bf16x8*)&Bs[(wn + ni * 16 + (lane & 15)) * 32 + ((lane >> 4) << 3)];
#pragma unroll
    for (int mi = 0; mi < 4; mi++)
#pragma unroll
      for (int ni = 0; ni < 4; ni++)
        acc[mi][ni] = __builtin_amdgcn_mfma_f32_16x16x32_bf16(af[mi], bf[ni], acc[mi][ni], 0, 0, 0);
  }

#pragma unroll
  for (int mi = 0; mi < 4; mi++) {
    int g = m0 + wm + mi * 16 + ((lane >> 4) << 2);
#pragma unroll
    for (int ni = 0; ni < 4; ni++) {
      int n = n0 + wn + ni * 16 + (lane & 15);
      int s = n >> 5, b = n & 31;
      ushort4 o = { f2bf(acc[mi][ni][0]), f2bf(acc[mi][ni][1]),
                    f2bf(acc[mi][ni][2]), f2bf(acc[mi][ni][3]) };
      *(ushort4*)(xg + ((size_t)(s * 6 + lg)) * (SB * HD) + (size_t)b * HD + g) = o;
    }
  }
}

// ---------------- phase 2: recurrence ----------------
// A-frag from swizzled LDS weights: row = lane&15, k = k0 + (lane>>4)*8
__device__ __forceinline__ bf16x8 afrag(const short* wlds, int gate, int lane, int k) {
  int r = lane & 15;
  int kk = k + ((lane >> 4) << 3);
  int ck = (kk >> 3) ^ (r & 7);
  return *(const bf16x8*)&wlds[gate * 16384 + r * HD + (ck << 3)];
}

// release-publish: data store (8B, agent), vmcnt(0), then flag store
__device__ __forceinline__ void publish(unsigned long long* dst, const f32x4 vals,
                                        unsigned* flagword, unsigned tag, int lane) {
  ushort4 o = { f2bf(vals[0]), f2bf(vals[1]), f2bf(vals[2]), f2bf(vals[3]) };
  unsigned long long q; __builtin_memcpy(&q, &o, 8);
  st_wt(dst, q);
  asm volatile("s_waitcnt vmcnt(0)" ::: "memory");   // data visible before flag
  if (lane == 0) st_flag(flagword, tag);
}

// acquire: every lane polls one producer flag
__device__ __forceinline__ void flag_wait64(const unsigned* fgrp, int lane, unsigned tag) {
  bool ok;
  do { ok = (ld_flag(&fgrp[lane * 16]) >= tag); } while (!__all(ok));
}

// issue this lane's 512B payload as 32 wide LLC-coherent plain loads (no wait)
__device__ __forceinline__ void stage_issue(const unsigned long long* p, u32x4* vv) {
#pragma unroll
  for (int kk = 0; kk < 32; kk++) {
    asm volatile("global_load_dwordx4 %0, %1, off sc0 sc1"
                 : "=v"(vv[kk]) : "v"(p + kk * 8) : "memory");
  }
}
// in-order vmcnt retirement (m135): vmcnt(16) => oldest (outstanding-16) done,
// which always includes stage loads 0..15 (any older ops only add slack).
__device__ __forceinline__ void wait_16() {
  asm volatile("s_waitcnt vmcnt(16)" ::: "memory");
  __builtin_amdgcn_sched_barrier(0);
}
__device__ __forceinline__ void wait_0() {
  asm volatile("s_waitcnt vmcnt(0)" ::: "memory");
  __builtin_amdgcn_sched_barrier(0);
}

__global__ __launch_bounds__(64, 1) void gru_rec(
    const float* __restrict__ h0,
    const float* __restrict__ Uz, const float* __restrict__ Ur, const float* __restrict__ Uh,
    const float* __restrict__ bz, const float* __restrict__ br, const float* __restrict__ bh,
    const unsigned short* __restrict__ xg,
    unsigned long long* __restrict__ hbuf,
    unsigned long long* __restrict__ rbuf,
    unsigned* __restrict__ hflg,
    unsigned* __restrict__ rflg,
    float* __restrict__ out) {
  __shared__ short wlds[3 * 16 * HD];   // 96 KB bf16 U-slices (1 WG/CU)

  const int wg = blockIdx.x;            // 256 WGs, one wave each
  const int l = wg >> 7;
  const int gs = wg & 63;
  const int g0 = gs * 16;
  const int b0 = ((wg >> 6) & 1) * 16;
  const int grp = wg >> 6;              // (l, b-half) group 0..3
  const int lane = threadIdx.x;
  const int col = lane & 15;
  const int sub = lane >> 4;
  const int rb = sub << 2;

  unsigned* hf_g = hflg + grp * 64 * 16;
  unsigned* rf_g = rflg + grp * 64 * 16;

  // ---- load U slices into LDS (bf16, XOR-swizzled 8-elem chunks) ----
  const float* Us[3] = { Uz, Ur, Uh };
#pragma unroll
  for (int gate = 0; gate < 3; gate++) {
    const float* U = Us[gate] + (size_t)l * HD * HD + (size_t)g0 * HD;
    for (int it = 0; it < 32; it++) {
      int chunk = it * 64 + lane;       // 2048 chunks of 8 elems
      int r = chunk >> 7;
      int ck = chunk & 127;
      const float* src = U + (size_t)r * HD + ck * 8;
      float4 a = *(const float4*)src;
      float4 bq = *(const float4*)(src + 4);
      bf16x8 o;
      o[0] = (short)f2bf(a.x); o[1] = (short)f2bf(a.y);
      o[2] = (short)f2bf(a.z); o[3] = (short)f2bf(a.w);
      o[4] = (short)f2bf(bq.x); o[5] = (short)f2bf(bq.y);
      o[6] = (short)f2bf(bq.z); o[7] = (short)f2bf(bq.w);
      int sck = ck ^ (r & 7);
      *(bf16x8*)&wlds[gate * 16384 + r * HD + sck * 8] = o;
    }
  }
  asm volatile("s_waitcnt lgkmcnt(0)" ::: "memory");  // single wave: LDS ready

  f32x4 vbz = *(const f32x4*)(bz + l * HD + g0 + rb);
  f32x4 vbr = *(const f32x4*)(br + l * HD + g0 + rb);
  f32x4 vbh = *(const f32x4*)(bh + l * HD + g0 + rb);

  const int brow = l * SB + b0 + col;                 // [L*B] row index
  f32x4 hreg = *(const f32x4*)(h0 + (size_t)brow * HD + g0 + rb);

  unsigned long long* hdst = hbuf + ((size_t)brow << 8) + ((g0 + rb) >> 2);
  unsigned long long* rdst = rbuf + ((size_t)brow << 8) + ((g0 + rb) >> 2);
  const unsigned long long* hp = hbuf + ((size_t)brow << 8) + sub * 2;
  const unsigned long long* rp = rbuf + ((size_t)brow << 8) + sub * 2;

  publish(hdst, hreg, &hf_g[gs * 16], 1u, lane);

  // xg current-step values, prefetched one step ahead
  size_t xb0 = ((size_t)l * 3) * (SB * HD) + (size_t)(b0 + col) * HD + g0 + rb;
  uint2 xzc = *(const uint2*)(xg + xb0);
  uint2 xrc = *(const uint2*)(xg + xb0 + SB * HD);
  uint2 xhc = *(const uint2*)(xg + xb0 + 2 * SB * HD);
  uint2 xzn, xrn, xhn;

  u32x4 vv[32];

  for (int s = 0; s < SEQ; s++) {
    const unsigned tag = (unsigned)(s + 1);

    // ---- phase A: r FIRST (critical path), then z (hidden) ----
    flag_wait64(hf_g, lane, tag);
    stage_issue(hp, vv);
    f32x4 ar0 = {0,0,0,0}, ar1 = {0,0,0,0};
    wait_16();                            // vv[0..15] valid
#pragma unroll
    for (int kk = 0; kk < 16; kk++) {
      union { u32x4 w; bf16x8 b; } u;
      u.w = vv[kk];
      bf16x8 wr = afrag(wlds, 1, lane, kk * 32);
      if (kk & 1) ar1 = __builtin_amdgcn_mfma_f32_16x16x32_bf16(wr, u.b, ar1, 0, 0, 0);
      else        ar0 = __builtin_amdgcn_mfma_f32_16x16x32_bf16(wr, u.b, ar0, 0, 0, 0);
    }
    wait_0();                             // vv[16..31] valid
#pragma unroll
    for (int kk = 16; kk < 32; kk++) {
      union { u32x4 w; bf16x8 b; } u;
      u.w = vv[kk];
      bf16x8 wr = afrag(wlds, 1, lane, kk * 32);
      if (kk & 1) ar1 = __builtin_amdgcn_mfma_f32_16x16x32_bf16(wr, u.b, ar1, 0, 0, 0);
      else        ar0 = __builtin_amdgcn_mfma_f32_16x16x32_bf16(wr, u.b, ar0, 0, 0, 0);
    }
    f32x4 accr = ar0 + ar1;
    f32x4 xrf = unpack4(xrc);
    f32x4 rh;
#pragma unroll
    for (int j = 0; j < 4; j++) {
      float ra = xrf[j] + vbr[j] + accr[j];
      rh[j] = (1.f / (1.f + __expf(-ra))) * hreg[j];
    }
    publish(rdst, rh, &rf_g[gs * 16], tag, lane);   // r*h released ASAP

    // prefetch next step's xg (in flight during z-compute + phase-B detect)
    {
      int sn = (s + 1 < SEQ) ? s + 1 : s;
      size_t xbn = ((size_t)sn * 6 + l * 3) * (SB * HD) + (size_t)(b0 + col) * HD + g0 + rb;
      xzn = *(const uint2*)(xg + xbn);
      xrn = *(const uint2*)(xg + xbn + SB * HD);
      xhn = *(const uint2*)(xg + xbn + 2 * SB * HD);
    }

    // z matvec + sigmoid — OFF the critical path (hidden under rh propagation)
    f32x4 az0 = {0,0,0,0}, az1 = {0,0,0,0};
#pragma unroll
    for (int kk = 0; kk < 32; kk++) {
      union { u32x4 w; bf16x8 b; } u;
      u.w = vv[kk];
      bf16x8 wz = afrag(wlds, 0, lane, kk * 32);
      if (kk & 1) az1 = __builtin_amdgcn_mfma_f32_16x16x32_bf16(wz, u.b, az1, 0, 0, 0);
      else        az0 = __builtin_amdgcn_mfma_f32_16x16x32_bf16(wz, u.b, az0, 0, 0, 0);
    }
    f32x4 accz = az0 + az1;
    f32x4 xzf = unpack4(xzc);
    f32x4 z;
#pragma unroll
    for (int j = 0; j < 4; j++) {
      float za = xzf[j] + vbz[j] + accz[j];
      z[j] = 1.f / (1.f + __expf(-za));
    }

    // ---- phase B: hh, h update ----
    flag_wait64(rf_g, lane, tag);
    stage_issue(rp, vv);
    f32x4 ah0 = {0,0,0,0}, ah1 = {0,0,0,0};
    wait_16();
#pragma unroll
    for (int kk = 0; kk < 16; kk++) {
      union { u32x4 w; bf16x8 b; } u;
      u.w = vv[kk];
      bf16x8 wh = afrag(wlds, 2, lane, kk * 32);
      if (kk & 1) ah1 = __builtin_amdgcn_mfma_f32_16x16x32_bf16(wh, u.b, ah1, 0, 0, 0);
      else        ah0 = __builtin_amdgcn_mfma_f32_16x16x32_bf16(wh, u.b, ah0, 0, 0, 0);
    }
    wait_0();
#pragma unroll
    for (int kk = 16; kk < 32; kk++) {
      union { u32x4 w; bf16x8 b; } u;
      u.w = vv[kk];
      bf16x8 wh = afrag(wlds, 2, lane, kk * 32);
      if (kk & 1) ah1 = __builtin_amdgcn_mfma_f32_16x16x32_bf16(wh, u.b, ah1, 0, 0, 0);
      else        ah0 = __builtin_amdgcn_mfma_f32_16x16x32_bf16(wh, u.b, ah0, 0, 0, 0);
    }
    f32x4 acch = ah0 + ah1;
    f32x4 xhf = unpack4(xhc);
#pragma unroll
    for (int j = 0; j < 4; j++) {
      float ha = xhf[j] + vbh[j] + acch[j];
      float e = __expf(2.f * ha);                    // tanh via exp
      float hh = 1.f - 2.f / (e + 1.f);
      hreg[j] = (1.f - z[j]) * hreg[j] + z[j] * hh;
    }
    publish(hdst, hreg, &hf_g[gs * 16], tag + 1, lane);

    if (l == 1)      // output stream is LAST layer only (after flag: off-path)
      *(f32x4*)(out + (size_t)s * (SB * HD) + (size_t)(b0 + col) * HD + g0 + rb) = hreg;
    if (s == SEQ - 1)
      *(f32x4*)(out + (size_t)SEQ * SB * HD + (size_t)brow * HD + g0 + rb) = hreg;

    xzc = xzn; xrc = xrn; xhc = xhn;
  }
}

extern "C" void kernel_launch(void* const* d_in, const int* in_sizes, int n_in,
                              void* d_out, int out_size, void* d_ws, size_t ws_size,
                              hipStream_t stream) {
  const float* x  = (const float*)d_in[0];
  const float* h0 = (const float*)d_in[1];
  const float* Wz = (const float*)d_in[2];
  const float* Wr = (const float*)d_in[3];
  const float* Wh = (const float*)d_in[4];
  const float* Uz = (const float*)d_in[5];
  const float* Ur = (const float*)d_in[6];
  const float* Uh = (const float*)d_in[7];
  const float* bz = (const float*)d_in[8];
  const float* br = (const float*)d_in[9];
  const float* bh = (const float*)d_in[10];

  char* ws = (char*)d_ws;
  unsigned short* xg  = (unsigned short*)(ws + XG_OFF);
  unsigned short* xbf = (unsigned short*)(ws + XBF_OFF);
  unsigned short* wbf = (unsigned short*)(ws + WBF_OFF);

  // clear flags (replay safety; data untagged, gated by flags)
  hipMemsetAsync(ws + HFLG_OFF, 0, FLG_WORDS * 8, stream);

  cvt_f32_bf16<<<1024, 256, 0, stream>>>(x, xbf, (int)(XBF_ELEMS / 4));
  const float* Wsrc[3] = { Wz, Wr, Wh };
  for (int gate = 0; gate < 3; gate++)
    for (int l = 0; l < 2; l++)
      cvt_f32_bf16<<<512, 256, 0, stream>>>(Wsrc[gate] + (size_t)l * HD * HD,
                                            wbf + ((size_t)(l * 3 + gate)) * HD * HD,
                                            HD * HD / 4);

  gemm_xg<<<dim3(128, 8, 6), 256, 0, stream>>>(wbf, xbf, xg);

  gru_rec<<<256, 64, 0, stream>>>(h0, Uz, Ur, Uh, bz, br, bh, xg,
                                  (unsigned long long*)(ws + HBUF_OFF),
                                  (unsigned long long*)(ws + RBUF_OFF),
                                  (unsigned*)(ws + HFLG_OFF),
                                  (unsigned*)(ws + RFLG_OFF),
                                  (float*)d_out);
}